// Round 2
// baseline (1573.781 us; speedup 1.0000x reference)
//
#include <hip/hip_runtime.h>
#include <hip/hip_bf16.h>

// ---- problem constants ----
constexpr int BDIM = 32, RDIM = 64, CDIM = 96, NH_ = 3, HD_ = 32;
constexpr int LTOK = RDIM * RDIM;      // 4096 tokens per image
constexpr int GG = 64;                 // tokens per 8x8 window
constexpr int HID = 384;
constexpr int NWIN = BDIM * (RDIM / 8) * (RDIM / 8);  // 2048
constexpr float SCALE = 0.17677669529663687f;          // 32^-0.5
constexpr long OUT1OFF = (long)BDIM * LTOK * CDIM;     // 12582912

struct P {
  const void *x, *w_qkv, *b_qkv, *w_lepe, *b_lepe, *w_proj, *b_proj;
  const void *g1, *bt1, *g2, *bt2, *w_fc1, *b_fc1, *w_fc2, *b_fc2;
  const int* flag;   // 1 = buffers are bf16, 0 = buffers are fp32
  void* out;
};

template <bool BF>
__device__ __forceinline__ float ldg(const void* p, long i) {
  if constexpr (BF) return __bfloat162float(((const __hip_bfloat16*)p)[i]);
  else return ((const float*)p)[i];
}
template <bool BF>
__device__ __forceinline__ void stg(void* p, long i, float v) {
  if constexpr (BF) ((__hip_bfloat16*)p)[i] = __float2bfloat16(v);
  else ((float*)p)[i] = v;
}

// ---- dtype detection: fp32 data read as 16-bit words has ~13% wild
// exponents (low mantissa halves are uniform bits); real bf16 N(0,1) ~0%.
__global__ void detect_dtype(const unsigned short* x, int* flag) {
  __shared__ int cnt;
  if (threadIdx.x == 0) cnt = 0;
  __syncthreads();
  int weird = 0;
  for (int k = 0; k < 4; ++k) {
    unsigned short u = x[threadIdx.x * 4 + k];
    int e = (u >> 7) & 0xFF;
    if (e == 0 || e >= 0xC0) weird++;   // zero/denormal or |v| >= 2^65 / inf / nan
  }
  atomicAdd(&cnt, weird);
  __syncthreads();
  if (threadIdx.x == 0) *flag = (cnt <= 32) ? 1 : 0;
}

// =====================================================================
// Kernel A: one 8x8 window per block. LN1 -> qkv -> attn(+LePE) -> proj
// -> x1 = x + o written into out[0..OUT1OFF) (staging for kernel B).
// attn probabilities written into out[OUT1OFF..).
// lane (tid&63) == token index within window for compute stages.
// LDS: bf16, stride 66 for transposed arrays (conflict-free both ways).
// =====================================================================
template <bool BF>
__global__ __launch_bounds__(256, 2)
void attn_win_kernel(P p) {
  if ((*p.flag != 0) != BF) return;   // wrong-dtype variant: no-op
  constexpr int SA = 66;
  __shared__ __hip_bfloat16 bufA[CDIM * SA];   // xT -> hT -> oT  (12.7 KB)
  __shared__ __hip_bfloat16 qkvT[288 * GG];    // q/k/v col-major (36.9 KB); projT overlays
  __shared__ __hip_bfloat16 sPad[GG * SA];     // scores, [col][row] (8.4 KB)
  __shared__ float meanS[GG], rstdS[GG];

  const int w = blockIdx.x;
  const int b = w >> 6, wi = w & 63, wr = wi >> 3, wc = wi & 7;
  const int tid = threadIdx.x;
  const int lane = tid & 63;
  const int wv = __builtin_amdgcn_readfirstlane(tid >> 6);
  const long xbase = (long)b * (LTOK * CDIM);

  // ---- load x window -> bufA (channel-major), coalesced per window-row ----
  for (int k = 0; k < 24; ++k) {
    int e = tid + k * 256;
    int wrow = e / 768;
    int o = e - wrow * 768;
    int tir = o / 96;
    int ch = o - tir * 96;
    long g = xbase + ((wr * 8 + wrow) * RDIM + wc * 8 + tir) * CDIM + ch;
    bufA[ch * SA + wrow * 8 + tir] = __float2bfloat16(ldg<BF>(p.x, g));
  }
  __syncthreads();

  // ---- LN1 stats (wave 0, lane = token) ----
  if (wv == 0) {
    float m = 0.f;
    for (int c = 0; c < CDIM; ++c) m += __bfloat162float(bufA[c * SA + lane]);
    m *= (1.f / CDIM);
    float var = 0.f;
    for (int c = 0; c < CDIM; ++c) {
      float d = __bfloat162float(bufA[c * SA + lane]) - m;
      var += d * d;
    }
    meanS[lane] = m;
    rstdS[lane] = rsqrtf(var * (1.f / CDIM) + 1e-5f);
  }
  __syncthreads();

  // ---- normalize in place; each wave owns a 24-channel slice ----
  {
    float m = meanS[lane], rs = rstdS[lane];
    for (int cc = 0; cc < 24; ++cc) {
      int c = wv * 24 + cc;
      float g = ldg<BF>(p.g1, c);
      float bt = ldg<BF>(p.bt1, c);
      float v = __bfloat162float(bufA[c * SA + lane]);
      bufA[c * SA + lane] = __float2bfloat16((v - m) * rs * g + bt);
    }
  }
  __syncthreads();

  // ---- qkv GEMM: lane = token, wave owns 72 columns (2 tiles of 36) ----
  for (int tile = 0; tile < 2; ++tile) {
    int j0 = wv * 72 + tile * 36;
    float acc[36];
#pragma unroll
    for (int jj = 0; jj < 36; ++jj) acc[jj] = ldg<BF>(p.b_qkv, j0 + jj);
#pragma unroll 1
    for (int c = 0; c < CDIM; ++c) {
      float hv = __bfloat162float(bufA[c * SA + lane]);
#pragma unroll
      for (int jj = 0; jj < 36; ++jj)
        acc[jj] += hv * ldg<BF>(p.w_qkv, c * 288 + j0 + jj);
    }
#pragma unroll
    for (int jj = 0; jj < 36; ++jj)
      qkvT[(j0 + jj) * GG + lane] = __float2bfloat16(acc[jj]);
  }
  __syncthreads();

  // ---- per-head: scores -> softmax(+attn out) -> attn@v + lepe ----
  for (int hh = 0; hh < NH_; ++hh) {
    // scores rows [wv*16, wv*16+16); lane = column j; k row held in regs
    float kreg[HD_];
#pragma unroll
    for (int d = 0; d < HD_; ++d)
      kreg[d] = __bfloat162float(qkvT[(CDIM + hh * HD_ + d) * GG + lane]);
#pragma unroll 1
    for (int r = 0; r < 16; ++r) {
      int i = wv * 16 + r;
      float acc = 0.f;
#pragma unroll
      for (int d = 0; d < HD_; ++d)
        acc += __bfloat162float(qkvT[(hh * HD_ + d) * GG + i]) * kreg[d];
      sPad[lane * SA + i] = __float2bfloat16(acc * SCALE);
    }
    // softmax on the same rows (same wave wrote them; no barrier needed)
#pragma unroll 1
    for (int r = 0; r < 16; ++r) {
      int i = wv * 16 + r;
      float v = __bfloat162float(sPad[lane * SA + i]);
      float mx = v;
#pragma unroll
      for (int s = 32; s > 0; s >>= 1) mx = fmaxf(mx, __shfl_xor(mx, s, 64));
      float e = __expf(v - mx);
      float sum = e;
#pragma unroll
      for (int s = 32; s > 0; s >>= 1) sum += __shfl_xor(sum, s, 64);
      float rr = e / sum;
      sPad[lane * SA + i] = __float2bfloat16(rr);
      stg<BF>(p.out, OUT1OFF + ((long)(w * NH_ + hh) * GG + i) * GG + lane, rr);
    }
    __syncthreads();

    // attn @ v + LePE: lane = token, wave owns d-range [wv*8, wv*8+8)
    {
      int d0 = wv * 8;
      float acc[8];
#pragma unroll
      for (int dd = 0; dd < 8; ++dd) acc[dd] = 0.f;
#pragma unroll 1
      for (int j = 0; j < GG; ++j) {
        float sv = __bfloat162float(sPad[j * SA + lane]);
#pragma unroll
        for (int dd = 0; dd < 8; ++dd)
          acc[dd] += sv * __bfloat162float(qkvT[(2 * CDIM + hh * HD_ + d0 + dd) * GG + j]);
      }
      int tr = lane >> 3, tc = lane & 7;
#pragma unroll
      for (int dd = 0; dd < 8; ++dd) {
        int c = hh * HD_ + d0 + dd;
        float a = ldg<BF>(p.b_lepe, c);
#pragma unroll
        for (int kh = 0; kh < 3; ++kh) {
#pragma unroll
          for (int kw = 0; kw < 3; ++kw) {
            int rr2 = tr + kh - 1, cc2 = tc + kw - 1;
            float wlv = ldg<BF>(p.w_lepe, c * 9 + kh * 3 + kw);
            float vv = 0.f;
            if (rr2 >= 0 && rr2 < 8 && cc2 >= 0 && cc2 < 8)
              vv = __bfloat162float(
                  qkvT[(2 * CDIM + hh * HD_ + d0 + dd) * GG + rr2 * 8 + cc2]);
            a += vv * wlv;
          }
        }
        acc[dd] += a;
      }
#pragma unroll
      for (int dd = 0; dd < 8; ++dd)
        bufA[(hh * HD_ + d0 + dd) * SA + lane] = __float2bfloat16(acc[dd]);
    }
    __syncthreads();  // sPad/qkvT reads done before next head overwrites sPad
  }

  // ---- proj: lane = token, wave owns 24 output channels ----
  __hip_bfloat16* projT = qkvT;  // 96x66 overlay; q/k regions dead now
  {
    int j0 = wv * 24;
    float acc[24];
#pragma unroll
    for (int jj = 0; jj < 24; ++jj) acc[jj] = ldg<BF>(p.b_proj, j0 + jj);
#pragma unroll 1
    for (int c = 0; c < CDIM; ++c) {
      float ov = __bfloat162float(bufA[c * SA + lane]);
#pragma unroll
      for (int jj = 0; jj < 24; ++jj)
        acc[jj] += ov * ldg<BF>(p.w_proj, c * CDIM + j0 + jj);
    }
#pragma unroll
    for (int jj = 0; jj < 24; ++jj)
      projT[(j0 + jj) * SA + lane] = __float2bfloat16(acc[jj]);
  }
  __syncthreads();

  // ---- x1 = x + o -> out (window-reversed, coalesced) ----
  for (int k = 0; k < 24; ++k) {
    int e = tid + k * 256;
    int wrow = e / 768;
    int o = e - wrow * 768;
    int tir = o / 96;
    int ch = o - tir * 96;
    long g = xbase + ((wr * 8 + wrow) * RDIM + wc * 8 + tir) * CDIM + ch;
    float v = ldg<BF>(p.x, g) + __bfloat162float(projT[ch * SA + wrow * 8 + tir]);
    stg<BF>(p.out, g, v);
  }
}

// =====================================================================
// Kernel B: 64 contiguous tokens per block. LN2 -> fc1+GELU -> fc2,
// out = x1 + m (x1 read back from out).
// =====================================================================
template <bool BF>
__global__ __launch_bounds__(256, 2)
void mlp_kernel(P p) {
  if ((*p.flag != 0) != BF) return;   // wrong-dtype variant: no-op
  constexpr int SB = 66;
  __shared__ __hip_bfloat16 bufB[CDIM * SB];   // x1T -> hT -> outT
  __shared__ __hip_bfloat16 hidT[HID * GG];    // 48 KB
  __shared__ float meanS[GG], rstdS[GG];

  const int tid = threadIdx.x, lane = tid & 63;
  const int wv = __builtin_amdgcn_readfirstlane(tid >> 6);
  const long t0 = (long)blockIdx.x * GG;

  for (int k = 0; k < 24; ++k) {
    int e = tid + k * 256;
    int tok = e / 96, ch = e - tok * 96;
    bufB[ch * SB + tok] = __float2bfloat16(ldg<BF>(p.out, (t0 + tok) * CDIM + ch));
  }
  __syncthreads();

  if (wv == 0) {
    float m = 0.f;
    for (int c = 0; c < CDIM; ++c) m += __bfloat162float(bufB[c * SB + lane]);
    m *= (1.f / CDIM);
    float var = 0.f;
    for (int c = 0; c < CDIM; ++c) {
      float d = __bfloat162float(bufB[c * SB + lane]) - m;
      var += d * d;
    }
    meanS[lane] = m;
    rstdS[lane] = rsqrtf(var * (1.f / CDIM) + 1e-5f);
  }
  __syncthreads();
  {
    float m = meanS[lane], rs = rstdS[lane];
    for (int cc = 0; cc < 24; ++cc) {
      int c = wv * 24 + cc;
      float g = ldg<BF>(p.g2, c);
      float bt = ldg<BF>(p.bt2, c);
      float v = __bfloat162float(bufB[c * SB + lane]);
      bufB[c * SB + lane] = __float2bfloat16((v - m) * rs * g + bt);
    }
  }
  __syncthreads();

  // fc1 + exact GELU: wave owns 96 hidden cols (4 tiles of 24)
  for (int tile = 0; tile < 4; ++tile) {
    int j0 = wv * 96 + tile * 24;
    float acc[24];
#pragma unroll
    for (int jj = 0; jj < 24; ++jj) acc[jj] = ldg<BF>(p.b_fc1, j0 + jj);
#pragma unroll 1
    for (int c = 0; c < CDIM; ++c) {
      float hv = __bfloat162float(bufB[c * SB + lane]);
#pragma unroll
      for (int jj = 0; jj < 24; ++jj)
        acc[jj] += hv * ldg<BF>(p.w_fc1, c * HID + j0 + jj);
    }
#pragma unroll
    for (int jj = 0; jj < 24; ++jj) {
      float xg = acc[jj];
      float gl = 0.5f * xg * (1.f + erff(xg * 0.70710678118f));
      hidT[(j0 + jj) * GG + lane] = __float2bfloat16(gl);
    }
  }
  __syncthreads();

  // fc2: wave owns 24 output channels
  {
    int j0 = wv * 24;
    float acc[24];
#pragma unroll
    for (int jj = 0; jj < 24; ++jj) acc[jj] = ldg<BF>(p.b_fc2, j0 + jj);
#pragma unroll 1
    for (int h = 0; h < HID; ++h) {
      float hv = __bfloat162float(hidT[h * GG + lane]);
#pragma unroll
      for (int jj = 0; jj < 24; ++jj)
        acc[jj] += hv * ldg<BF>(p.w_fc2, h * CDIM + j0 + jj);
    }
#pragma unroll
    for (int jj = 0; jj < 24; ++jj)
      bufB[(j0 + jj) * SB + lane] = __float2bfloat16(acc[jj]);  // bufB dead post-fc1
  }
  __syncthreads();

  for (int k = 0; k < 24; ++k) {
    int e = tid + k * 256;
    int tok = e / 96, ch = e - tok * 96;
    long g = (t0 + tok) * CDIM + ch;
    float v = ldg<BF>(p.out, g) + __bfloat162float(bufB[ch * SB + tok]);
    stg<BF>(p.out, g, v);
  }
}

extern "C" void kernel_launch(void* const* d_in, const int* in_sizes, int n_in,
                              void* d_out, int out_size, void* d_ws, size_t ws_size,
                              hipStream_t stream) {
  P p;
  p.x      = d_in[0];
  p.w_qkv  = d_in[1];
  p.b_qkv  = d_in[2];
  p.w_lepe = d_in[3];
  p.b_lepe = d_in[4];
  p.w_proj = d_in[5];
  p.b_proj = d_in[6];
  p.g1     = d_in[7];
  p.bt1    = d_in[8];
  p.g2     = d_in[9];
  p.bt2    = d_in[10];
  p.w_fc1  = d_in[11];
  p.b_fc1  = d_in[12];
  p.w_fc2  = d_in[13];
  p.b_fc2  = d_in[14];
  p.flag   = (const int*)d_ws;
  p.out    = d_out;

  detect_dtype<<<1, 256, 0, stream>>>((const unsigned short*)d_in[0], (int*)d_ws);

  const int mlp_blocks = (BDIM * LTOK) / GG;  // 2048
  attn_win_kernel<true ><<<NWIN, 256, 0, stream>>>(p);
  attn_win_kernel<false><<<NWIN, 256, 0, stream>>>(p);
  mlp_kernel<true ><<<mlp_blocks, 256, 0, stream>>>(p);
  mlp_kernel<false><<<mlp_blocks, 256, 0, stream>>>(p);
}

// Round 3
// 425.798 us; speedup vs baseline: 3.6961x; 3.6961x over previous
//
#include <hip/hip_runtime.h>
#include <hip/hip_bf16.h>

typedef short short8 __attribute__((ext_vector_type(8)));
typedef float f32x4 __attribute__((ext_vector_type(4)));

constexpr int BDIM = 32, RDIM = 64, CDIM = 96, NH_ = 3, HD_ = 32;
constexpr int LTOK = RDIM * RDIM;      // 4096
constexpr int GG = 64;
constexpr int HID = 384;
constexpr int NWIN = 2048;
constexpr float SCALE = 0.17677669529663687f;
constexpr long OUT1OFF = (long)BDIM * LTOK * CDIM;   // 12582912

// ws layout (bf16 element offsets): transposed weights [n][k], k-contiguous
constexpr int O_WQKVT = 0;        // [288][96]
constexpr int O_WPROJT = 27648;   // [96][96]
constexpr int O_WFC1T = 36864;    // [384][96]
constexpr int O_WFC2T = 73728;    // [96][384]
constexpr int W_TOT = 110592;

__device__ __forceinline__ unsigned short f2b(float f) {
  return __builtin_bit_cast(unsigned short, __float2bfloat16(f));
}
__device__ __forceinline__ float b2f(unsigned short u) {
  return __bfloat162float(__builtin_bit_cast(__hip_bfloat16, u));
}

// ---------------- weight transpose+cvt prep ----------------
__global__ void prep_weights(const float* __restrict__ wqkv,
                             const float* __restrict__ wproj,
                             const float* __restrict__ wfc1,
                             const float* __restrict__ wfc2,
                             unsigned short* __restrict__ ws) {
  int i = blockIdx.x * 256 + threadIdx.x;
  if (i >= W_TOT) return;
  float v;
  if (i < O_WPROJT) {
    int n = i / 96, k = i - n * 96;
    v = wqkv[k * 288 + n];
  } else if (i < O_WFC1T) {
    int j = i - O_WPROJT, n = j / 96, k = j - n * 96;
    v = wproj[k * 96 + n];
  } else if (i < O_WFC2T) {
    int j = i - O_WFC1T, n = j / 96, k = j - n * 96;
    v = wfc1[k * 384 + n];
  } else {
    int j = i - O_WFC2T, n = j / 384, k = j - n * 384;
    v = wfc2[k * 96 + n];
  }
  ws[i] = f2b(v);
}

// =====================================================================
// Kernel A (MFMA): one 8x8 window per block, 4 waves; wave = 16-row m-tile.
// LN1 -> qkv (MFMA) -> per-head S (MFMA) -> softmax -> PV (MFMA) + LePE
// -> proj (MFMA) -> x1 = x + o.
// =====================================================================
__global__ __launch_bounds__(256, 2)
void attn_mfma(const float* __restrict__ x, const float* __restrict__ bqkv,
               const float* __restrict__ wlepe, const float* __restrict__ blepe,
               const float* __restrict__ bproj, const float* __restrict__ g1,
               const float* __restrict__ bt1,
               const unsigned short* __restrict__ ws, float* __restrict__ out) {
  constexpr int SA = 104;   // hA/O stride (bf16 elems); 208B, 16B-aligned, 2-way banks
  constexpr int SQ = 200;   // qkS stride (q cols 0..95, k cols 96..191)
  constexpr int SV = 72;    // vS stride
  constexpr int SP = 72;    // pS stride
  __shared__ __attribute__((aligned(16))) unsigned short hA[64 * SA];   // h, later O
  __shared__ __attribute__((aligned(16))) unsigned short qkS[64 * SQ];
  __shared__ __attribute__((aligned(16))) unsigned short vS[96 * SV];
  __shared__ __attribute__((aligned(16))) unsigned short pS[64 * SP];
  float* red = (float*)pS;  // LN scratch, dead before pS's first use

  const int tid = threadIdx.x, lane = tid & 63;
  const int wv = __builtin_amdgcn_readfirstlane(tid >> 6);
  const int w = blockIdx.x, b = w >> 6, wi = w & 63, wr = wi >> 3, wc = wi & 7;
  const long xbase = (long)b * (LTOK * CDIM);
  const int l15 = lane & 15, lk = (lane >> 4) * 8, lr = (lane >> 4) * 4;

  // ---- load + LN1: thread owns (token=lane, channel-quarter=wv) ----
  {
    const int tok = lane;
    const long rowbase =
        xbase + (long)((wr * 8 + (tok >> 3)) * RDIM + wc * 8 + (tok & 7)) * CDIM;
    float xv[24], s1 = 0.f, s2 = 0.f;
#pragma unroll
    for (int i = 0; i < 24; ++i) {
      float v = x[rowbase + wv * 24 + i];
      xv[i] = v; s1 += v; s2 += v * v;
    }
    red[wv * 64 + tok] = s1;
    red[256 + wv * 64 + tok] = s2;
    __syncthreads();
    float m = 0.f, vv = 0.f;
#pragma unroll
    for (int q = 0; q < 4; ++q) { m += red[q * 64 + tok]; vv += red[256 + q * 64 + tok]; }
    m *= (1.f / 96.f);
    vv = vv * (1.f / 96.f) - m * m;
    float rs = rsqrtf(vv + 1e-5f);
#pragma unroll
    for (int i = 0; i < 24; ++i) {
      int c = wv * 24 + i;
      hA[tok * SA + c] = f2b((xv[i] - m) * rs * g1[c] + bt1[c]);
    }
  }
  __syncthreads();

  // ---- qkv: wave's 16 rows x 288 cols ----
  {
    f32x4 acc[18];
#pragma unroll
    for (int t = 0; t < 18; ++t) acc[t] = (f32x4){0.f, 0.f, 0.f, 0.f};
    const int arow = wv * 16 + l15;
#pragma unroll
    for (int kk = 0; kk < 3; ++kk) {
      short8 a = *(const short8*)&hA[arow * SA + kk * 32 + lk];
#pragma unroll
      for (int nt = 0; nt < 18; ++nt) {
        short8 bw = *(const short8*)&ws[O_WQKVT + (nt * 16 + l15) * 96 + kk * 32 + lk];
        acc[nt] = __builtin_amdgcn_mfma_f32_16x16x32_bf16(a, bw, acc[nt], 0, 0, 0);
      }
    }
    // stage q (scaled), k, v with bias
#pragma unroll
    for (int nt = 0; nt < 18; ++nt) {
      int n0 = nt * 16 + l15;
      float bias = bqkv[n0];
#pragma unroll
      for (int r = 0; r < 4; ++r) {
        int tk = wv * 16 + lr + r;
        float v = acc[nt][r] + bias;
        if (n0 < 96) qkS[tk * SQ + n0] = f2b(v * SCALE);
        else if (n0 < 192) qkS[tk * SQ + n0] = f2b(v);
        else vS[(n0 - 192) * SV + tk] = f2b(v);
      }
    }
  }
  __syncthreads();

  // ---- per-head attention ----
  for (int h = 0; h < NH_; ++h) {
    f32x4 sacc[4];
#pragma unroll
    for (int t = 0; t < 4; ++t) sacc[t] = (f32x4){0.f, 0.f, 0.f, 0.f};
    short8 aq = *(const short8*)&qkS[(wv * 16 + l15) * SQ + h * 32 + lk];
#pragma unroll
    for (int nt = 0; nt < 4; ++nt) {
      short8 bk = *(const short8*)&qkS[(nt * 16 + l15) * SQ + 96 + h * 32 + lk];
      sacc[nt] = __builtin_amdgcn_mfma_f32_16x16x32_bf16(aq, bk, sacc[nt], 0, 0, 0);
    }
    // softmax (rows live in 16-lane groups)
    float p[4][4];
#pragma unroll
    for (int r = 0; r < 4; ++r) {
      float mx = -1e30f;
#pragma unroll
      for (int nt = 0; nt < 4; ++nt) mx = fmaxf(mx, sacc[nt][r]);
#pragma unroll
      for (int s = 1; s < 16; s <<= 1) mx = fmaxf(mx, __shfl_xor(mx, s, 64));
      float sum = 0.f;
#pragma unroll
      for (int nt = 0; nt < 4; ++nt) {
        float e = __expf(sacc[nt][r] - mx);
        p[nt][r] = e; sum += e;
      }
#pragma unroll
      for (int s = 1; s < 16; s <<= 1) sum += __shfl_xor(sum, s, 64);
      float inv = 1.f / sum;
#pragma unroll
      for (int nt = 0; nt < 4; ++nt) p[nt][r] *= inv;
    }
    // write attn probs (fp32) + stage P (bf16, wave-local rows)
    const long o1base = OUT1OFF + ((long)(w * NH_ + h) * GG) * GG;
#pragma unroll
    for (int nt = 0; nt < 4; ++nt) {
      int col = nt * 16 + l15;
#pragma unroll
      for (int r = 0; r < 4; ++r) {
        int row = wv * 16 + lr + r;
        out[o1base + (long)row * GG + col] = p[nt][r];
        pS[row * SP + col] = f2b(p[nt][r]);
      }
    }
    // PV (same wave produced pS rows; vS covered by post-staging barrier)
    f32x4 oa[2];
    oa[0] = (f32x4){0.f, 0.f, 0.f, 0.f};
    oa[1] = (f32x4){0.f, 0.f, 0.f, 0.f};
#pragma unroll
    for (int kk = 0; kk < 2; ++kk) {
      short8 ap = *(const short8*)&pS[(wv * 16 + l15) * SP + kk * 32 + lk];
#pragma unroll
      for (int nt = 0; nt < 2; ++nt) {
        short8 bv = *(const short8*)&vS[(h * 32 + nt * 16 + l15) * SV + kk * 32 + lk];
        oa[nt] = __builtin_amdgcn_mfma_f32_16x16x32_bf16(ap, bv, oa[nt], 0, 0, 0);
      }
    }
    // LePE + write O into hA (wave-exclusive rows)
#pragma unroll
    for (int nt = 0; nt < 2; ++nt) {
      int d = nt * 16 + l15, c = h * 32 + d;
      float lw9[9];
#pragma unroll
      for (int q = 0; q < 9; ++q) lw9[q] = wlepe[c * 9 + q];
      float lb = blepe[c];
#pragma unroll
      for (int r = 0; r < 4; ++r) {
        int tk = wv * 16 + lr + r;
        int tr_ = tk >> 3, tc_ = tk & 7;
        float a = lb;
#pragma unroll
        for (int kh = 0; kh < 3; ++kh)
#pragma unroll
          for (int kw2 = 0; kw2 < 3; ++kw2) {
            int rr = tr_ + kh - 1, cc = tc_ + kw2 - 1;
            if (rr >= 0 && rr < 8 && cc >= 0 && cc < 8)
              a += lw9[kh * 3 + kw2] * b2f(vS[c * SV + rr * 8 + cc]);
          }
        hA[tk * SA + c] = f2b(oa[nt][r] + a);
      }
    }
  }
  __syncthreads();

  // ---- proj + residual epilogue ----
  {
    f32x4 pacc[6];
#pragma unroll
    for (int t = 0; t < 6; ++t) pacc[t] = (f32x4){0.f, 0.f, 0.f, 0.f};
#pragma unroll
    for (int kk = 0; kk < 3; ++kk) {
      short8 ao = *(const short8*)&hA[(wv * 16 + l15) * SA + kk * 32 + lk];
#pragma unroll
      for (int nt = 0; nt < 6; ++nt) {
        short8 bw = *(const short8*)&ws[O_WPROJT + (nt * 16 + l15) * 96 + kk * 32 + lk];
        pacc[nt] = __builtin_amdgcn_mfma_f32_16x16x32_bf16(ao, bw, pacc[nt], 0, 0, 0);
      }
    }
#pragma unroll
    for (int nt = 0; nt < 6; ++nt) {
      int ch = nt * 16 + l15;
      float bias = bproj[ch];
#pragma unroll
      for (int r = 0; r < 4; ++r) {
        int tk = wv * 16 + lr + r;
        long g = xbase + (long)((wr * 8 + (tk >> 3)) * RDIM + wc * 8 + (tk & 7)) * CDIM + ch;
        out[g] = x[g] + pacc[nt][r] + bias;
      }
    }
  }
}

// =====================================================================
// Kernel B (MFMA): 64 tokens per block. LN2 -> fc1+GELU -> fc2 -> +x1.
// =====================================================================
__global__ __launch_bounds__(256, 2)
void mlp_mfma(const float* __restrict__ bfc1, const float* __restrict__ bfc2,
              const float* __restrict__ g2, const float* __restrict__ bt2,
              const unsigned short* __restrict__ ws, float* __restrict__ out) {
  constexpr int SB = 104, SH = 392;
  __shared__ __attribute__((aligned(16))) unsigned short hB[64 * SB];
  __shared__ __attribute__((aligned(16))) unsigned short Hs[64 * SH];
  float* red = (float*)Hs;  // LN scratch, dead before Hs's first write

  const int tid = threadIdx.x, lane = tid & 63;
  const int wv = __builtin_amdgcn_readfirstlane(tid >> 6);
  const long t0 = (long)blockIdx.x * GG;
  const int l15 = lane & 15, lk = (lane >> 4) * 8, lr = (lane >> 4) * 4;

  // ---- load x1 + LN2 ----
  {
    const int tok = lane;
    const long rb = (t0 + tok) * CDIM;
    float xv[24], s1 = 0.f, s2 = 0.f;
#pragma unroll
    for (int i = 0; i < 24; ++i) {
      float v = out[rb + wv * 24 + i];
      xv[i] = v; s1 += v; s2 += v * v;
    }
    red[wv * 64 + tok] = s1;
    red[256 + wv * 64 + tok] = s2;
    __syncthreads();
    float m = 0.f, vv = 0.f;
#pragma unroll
    for (int q = 0; q < 4; ++q) { m += red[q * 64 + tok]; vv += red[256 + q * 64 + tok]; }
    m *= (1.f / 96.f);
    vv = vv * (1.f / 96.f) - m * m;
    float rs = rsqrtf(vv + 1e-5f);
#pragma unroll
    for (int i = 0; i < 24; ++i) {
      int c = wv * 24 + i;
      hB[tok * SB + c] = f2b((xv[i] - m) * rs * g2[c] + bt2[c]);
    }
  }
  __syncthreads();

  // ---- fc1 + exact GELU (two halves of 192 cols to cap VGPRs) ----
  for (int half = 0; half < 2; ++half) {
    f32x4 acc[12];
#pragma unroll
    for (int t = 0; t < 12; ++t) acc[t] = (f32x4){0.f, 0.f, 0.f, 0.f};
#pragma unroll
    for (int kk = 0; kk < 3; ++kk) {
      short8 a = *(const short8*)&hB[(wv * 16 + l15) * SB + kk * 32 + lk];
#pragma unroll
      for (int nt = 0; nt < 12; ++nt) {
        int n = half * 192 + nt * 16 + l15;
        short8 bw = *(const short8*)&ws[O_WFC1T + n * 96 + kk * 32 + lk];
        acc[nt] = __builtin_amdgcn_mfma_f32_16x16x32_bf16(a, bw, acc[nt], 0, 0, 0);
      }
    }
#pragma unroll
    for (int nt = 0; nt < 12; ++nt) {
      int n = half * 192 + nt * 16 + l15;
      float bias = bfc1[n];
#pragma unroll
      for (int r = 0; r < 4; ++r) {
        int tk = wv * 16 + lr + r;
        float v = acc[nt][r] + bias;
        float gl = 0.5f * v * (1.f + erff(v * 0.70710678118654752f));
        Hs[tk * SH + n] = f2b(gl);
      }
    }
  }
  __syncthreads();

  // ---- fc2 + residual ----
  {
    f32x4 acc[6];
#pragma unroll
    for (int t = 0; t < 6; ++t) acc[t] = (f32x4){0.f, 0.f, 0.f, 0.f};
#pragma unroll
    for (int kk = 0; kk < 12; ++kk) {
      short8 a = *(const short8*)&Hs[(wv * 16 + l15) * SH + kk * 32 + lk];
#pragma unroll
      for (int nt = 0; nt < 6; ++nt) {
        short8 bw = *(const short8*)&ws[O_WFC2T + (nt * 16 + l15) * 384 + kk * 32 + lk];
        acc[nt] = __builtin_amdgcn_mfma_f32_16x16x32_bf16(a, bw, acc[nt], 0, 0, 0);
      }
    }
#pragma unroll
    for (int nt = 0; nt < 6; ++nt) {
      int ch = nt * 16 + l15;
      float bias = bfc2[ch];
#pragma unroll
      for (int r = 0; r < 4; ++r) {
        int tk = wv * 16 + lr + r;
        long g = (t0 + tk) * CDIM + ch;
        out[g] = out[g] + acc[nt][r] + bias;
      }
    }
  }
}

// =====================================================================
// Scalar fallback (round-2 proven path), used only if ws too small.
// =====================================================================
struct PF {
  const float *x, *w_qkv, *b_qkv, *w_lepe, *b_lepe, *w_proj, *b_proj;
  const float *g1, *bt1, *g2, *bt2, *w_fc1, *b_fc1, *w_fc2, *b_fc2;
  float* out;
};

__global__ __launch_bounds__(256, 2)
void attn_scalar(PF p) {
  constexpr int SA = 66;
  __shared__ __hip_bfloat16 bufA[CDIM * SA];
  __shared__ __hip_bfloat16 qkvT[288 * GG];
  __shared__ __hip_bfloat16 sPad[GG * SA];
  __shared__ float meanS[GG], rstdS[GG];

  const int w = blockIdx.x;
  const int b = w >> 6, wi = w & 63, wr = wi >> 3, wc = wi & 7;
  const int tid = threadIdx.x, lane = tid & 63;
  const int wv = __builtin_amdgcn_readfirstlane(tid >> 6);
  const long xbase = (long)b * (LTOK * CDIM);

  for (int k = 0; k < 24; ++k) {
    int e = tid + k * 256, wrow = e / 768, o = e - wrow * 768;
    int tir = o / 96, ch = o - tir * 96;
    long g = xbase + ((wr * 8 + wrow) * RDIM + wc * 8 + tir) * CDIM + ch;
    bufA[ch * SA + wrow * 8 + tir] = __float2bfloat16(p.x[g]);
  }
  __syncthreads();
  if (wv == 0) {
    float m = 0.f;
    for (int c = 0; c < CDIM; ++c) m += __bfloat162float(bufA[c * SA + lane]);
    m *= (1.f / CDIM);
    float var = 0.f;
    for (int c = 0; c < CDIM; ++c) {
      float d = __bfloat162float(bufA[c * SA + lane]) - m;
      var += d * d;
    }
    meanS[lane] = m;
    rstdS[lane] = rsqrtf(var * (1.f / CDIM) + 1e-5f);
  }
  __syncthreads();
  {
    float m = meanS[lane], rs = rstdS[lane];
    for (int cc = 0; cc < 24; ++cc) {
      int c = wv * 24 + cc;
      float v = __bfloat162float(bufA[c * SA + lane]);
      bufA[c * SA + lane] = __float2bfloat16((v - m) * rs * p.g1[c] + p.bt1[c]);
    }
  }
  __syncthreads();
  for (int tile = 0; tile < 2; ++tile) {
    int j0 = wv * 72 + tile * 36;
    float acc[36];
#pragma unroll
    for (int jj = 0; jj < 36; ++jj) acc[jj] = p.b_qkv[j0 + jj];
#pragma unroll 1
    for (int c = 0; c < CDIM; ++c) {
      float hv = __bfloat162float(bufA[c * SA + lane]);
#pragma unroll
      for (int jj = 0; jj < 36; ++jj) acc[jj] += hv * p.w_qkv[c * 288 + j0 + jj];
    }
#pragma unroll
    for (int jj = 0; jj < 36; ++jj)
      qkvT[(j0 + jj) * GG + lane] = __float2bfloat16(acc[jj]);
  }
  __syncthreads();
  for (int hh = 0; hh < NH_; ++hh) {
    float kreg[HD_];
#pragma unroll
    for (int d = 0; d < HD_; ++d)
      kreg[d] = __bfloat162float(qkvT[(CDIM + hh * HD_ + d) * GG + lane]);
#pragma unroll 1
    for (int r = 0; r < 16; ++r) {
      int i = wv * 16 + r;
      float acc = 0.f;
#pragma unroll
      for (int d = 0; d < HD_; ++d)
        acc += __bfloat162float(qkvT[(hh * HD_ + d) * GG + i]) * kreg[d];
      sPad[lane * SA + i] = __float2bfloat16(acc * SCALE);
    }
#pragma unroll 1
    for (int r = 0; r < 16; ++r) {
      int i = wv * 16 + r;
      float v = __bfloat162float(sPad[lane * SA + i]);
      float mx = v;
#pragma unroll
      for (int s = 32; s > 0; s >>= 1) mx = fmaxf(mx, __shfl_xor(mx, s, 64));
      float e = __expf(v - mx);
      float sum = e;
#pragma unroll
      for (int s = 32; s > 0; s >>= 1) sum += __shfl_xor(sum, s, 64);
      float rr = e / sum;
      sPad[lane * SA + i] = __float2bfloat16(rr);
      p.out[OUT1OFF + ((long)(w * NH_ + hh) * GG + i) * GG + lane] = rr;
    }
    __syncthreads();
    {
      int d0 = wv * 8;
      float acc[8];
#pragma unroll
      for (int dd = 0; dd < 8; ++dd) acc[dd] = 0.f;
#pragma unroll 1
      for (int j = 0; j < GG; ++j) {
        float sv = __bfloat162float(sPad[j * SA + lane]);
#pragma unroll
        for (int dd = 0; dd < 8; ++dd)
          acc[dd] += sv * __bfloat162float(qkvT[(2 * CDIM + hh * HD_ + d0 + dd) * GG + j]);
      }
      int tr = lane >> 3, tc = lane & 7;
#pragma unroll
      for (int dd = 0; dd < 8; ++dd) {
        int c = hh * HD_ + d0 + dd;
        float a = p.b_lepe[c];
#pragma unroll
        for (int kh = 0; kh < 3; ++kh)
#pragma unroll
          for (int kw = 0; kw < 3; ++kw) {
            int rr2 = tr + kh - 1, cc2 = tc + kw - 1;
            if (rr2 >= 0 && rr2 < 8 && cc2 >= 0 && cc2 < 8)
              a += p.w_lepe[c * 9 + kh * 3 + kw] *
                   __bfloat162float(qkvT[(2 * CDIM + hh * HD_ + d0 + dd) * GG + rr2 * 8 + cc2]);
          }
        acc[dd] += a;
      }
#pragma unroll
      for (int dd = 0; dd < 8; ++dd)
        bufA[(hh * HD_ + d0 + dd) * SA + lane] = __float2bfloat16(acc[dd]);
    }
    __syncthreads();
  }
  __hip_bfloat16* projT = qkvT;
  {
    int j0 = wv * 24;
    float acc[24];
#pragma unroll
    for (int jj = 0; jj < 24; ++jj) acc[jj] = p.b_proj[j0 + jj];
#pragma unroll 1
    for (int c = 0; c < CDIM; ++c) {
      float ov = __bfloat162float(bufA[c * SA + lane]);
#pragma unroll
      for (int jj = 0; jj < 24; ++jj) acc[jj] += ov * p.w_proj[c * CDIM + j0 + jj];
    }
#pragma unroll
    for (int jj = 0; jj < 24; ++jj)
      projT[(j0 + jj) * SA + lane] = __float2bfloat16(acc[jj]);
  }
  __syncthreads();
  for (int k = 0; k < 24; ++k) {
    int e = tid + k * 256, wrow = e / 768, o = e - wrow * 768;
    int tir = o / 96, ch = o - tir * 96;
    long g = xbase + ((wr * 8 + wrow) * RDIM + wc * 8 + tir) * CDIM + ch;
    p.out[g] = p.x[g] + __bfloat162float(projT[ch * SA + wrow * 8 + tir]);
  }
}

__global__ __launch_bounds__(256, 2)
void mlp_scalar(PF p) {
  constexpr int SB = 66;
  __shared__ __hip_bfloat16 bufB[CDIM * SB];
  __shared__ __hip_bfloat16 hidT[HID * GG];
  __shared__ float meanS[GG], rstdS[GG];

  const int tid = threadIdx.x, lane = tid & 63;
  const int wv = __builtin_amdgcn_readfirstlane(tid >> 6);
  const long t0 = (long)blockIdx.x * GG;

  for (int k = 0; k < 24; ++k) {
    int e = tid + k * 256, tok = e / 96, ch = e - tok * 96;
    bufB[ch * SB + tok] = __float2bfloat16(p.out[(t0 + tok) * CDIM + ch]);
  }
  __syncthreads();
  if (wv == 0) {
    float m = 0.f;
    for (int c = 0; c < CDIM; ++c) m += __bfloat162float(bufB[c * SB + lane]);
    m *= (1.f / CDIM);
    float var = 0.f;
    for (int c = 0; c < CDIM; ++c) {
      float d = __bfloat162float(bufB[c * SB + lane]) - m;
      var += d * d;
    }
    meanS[lane] = m;
    rstdS[lane] = rsqrtf(var * (1.f / CDIM) + 1e-5f);
  }
  __syncthreads();
  {
    float m = meanS[lane], rs = rstdS[lane];
    for (int cc = 0; cc < 24; ++cc) {
      int c = wv * 24 + cc;
      float v = __bfloat162float(bufB[c * SB + lane]);
      bufB[c * SB + lane] = __float2bfloat16((v - m) * rs * p.g2[c] + p.bt2[c]);
    }
  }
  __syncthreads();
  for (int tile = 0; tile < 4; ++tile) {
    int j0 = wv * 96 + tile * 24;
    float acc[24];
#pragma unroll
    for (int jj = 0; jj < 24; ++jj) acc[jj] = p.b_fc1[j0 + jj];
#pragma unroll 1
    for (int c = 0; c < CDIM; ++c) {
      float hv = __bfloat162float(bufB[c * SB + lane]);
#pragma unroll
      for (int jj = 0; jj < 24; ++jj) acc[jj] += hv * p.w_fc1[c * HID + j0 + jj];
    }
#pragma unroll
    for (int jj = 0; jj < 24; ++jj) {
      float xg = acc[jj];
      hidT[(j0 + jj) * GG + lane] =
          __float2bfloat16(0.5f * xg * (1.f + erff(xg * 0.70710678118f)));
    }
  }
  __syncthreads();
  {
    int j0 = wv * 24;
    float acc[24];
#pragma unroll
    for (int jj = 0; jj < 24; ++jj) acc[jj] = p.b_fc2[j0 + jj];
#pragma unroll 1
    for (int h = 0; h < HID; ++h) {
      float hv = __bfloat162float(hidT[h * GG + lane]);
#pragma unroll
      for (int jj = 0; jj < 24; ++jj) acc[jj] += hv * p.w_fc2[h * CDIM + j0 + jj];
    }
#pragma unroll
    for (int jj = 0; jj < 24; ++jj)
      bufB[(j0 + jj) * SB + lane] = __float2bfloat16(acc[jj]);
  }
  __syncthreads();
  for (int k = 0; k < 24; ++k) {
    int e = tid + k * 256, tok = e / 96, ch = e - tok * 96;
    long g = (t0 + tok) * CDIM + ch;
    p.out[g] = p.out[g] + __bfloat162float(bufB[ch * SB + tok]);
  }
}

extern "C" void kernel_launch(void* const* d_in, const int* in_sizes, int n_in,
                              void* d_out, int out_size, void* d_ws, size_t ws_size,
                              hipStream_t stream) {
  const float* x = (const float*)d_in[0];
  const float* w_qkv = (const float*)d_in[1];
  const float* b_qkv = (const float*)d_in[2];
  const float* w_lepe = (const float*)d_in[3];
  const float* b_lepe = (const float*)d_in[4];
  const float* w_proj = (const float*)d_in[5];
  const float* b_proj = (const float*)d_in[6];
  const float* g1 = (const float*)d_in[7];
  const float* bt1 = (const float*)d_in[8];
  const float* g2 = (const float*)d_in[9];
  const float* bt2 = (const float*)d_in[10];
  const float* w_fc1 = (const float*)d_in[11];
  const float* b_fc1 = (const float*)d_in[12];
  const float* w_fc2 = (const float*)d_in[13];
  const float* b_fc2 = (const float*)d_in[14];
  float* out = (float*)d_out;
  const int mlp_blocks = (BDIM * LTOK) / GG;  // 2048

  if (ws_size >= (size_t)W_TOT * sizeof(unsigned short)) {
    unsigned short* ws = (unsigned short*)d_ws;
    prep_weights<<<(W_TOT + 255) / 256, 256, 0, stream>>>(w_qkv, w_proj, w_fc1, w_fc2, ws);
    attn_mfma<<<NWIN, 256, 0, stream>>>(x, b_qkv, w_lepe, b_lepe, b_proj, g1, bt1, ws, out);
    mlp_mfma<<<mlp_blocks, 256, 0, stream>>>(b_fc1, b_fc2, g2, bt2, ws, out);
  } else {
    PF p{x, w_qkv, b_qkv, w_lepe, b_lepe, w_proj, b_proj,
         g1, bt1, g2, bt2, w_fc1, b_fc1, w_fc2, b_fc2, out};
    attn_scalar<<<NWIN, 256, 0, stream>>>(p);
    mlp_scalar<<<mlp_blocks, 256, 0, stream>>>(p);
  }
}